// Round 12
// baseline (1261.702 us; speedup 1.0000x reference)
//
#include <hip/hip_runtime.h>

// ChildSumTreeLSTMCell — round 12: R8 skeleton + pair-interleaved columns.
// 32 nodes/block, 512 threads, 2 blocks/CU.
// B-buffers store column pairs: frag tile t, slot j -> global col
// (t>>1)*32 + 2j + (t&1). Each lane owns 2 CONTIGUOUS cols ->
//   cm = 8 x dwordx2, ct write = dwordx2, wfs = packed u32, biases dwordx2.
// iou: 2 passes over row-halves (rt), both col-tiles per pass -> epilogue
// writes h,c DIRECTLY to global (128-B segments), no IUOp LDS, 9 barriers.

typedef __attribute__((ext_vector_type(8))) short short8;
typedef __attribute__((ext_vector_type(4))) float f32x4;
typedef __attribute__((ext_vector_type(2))) float f32x2;
typedef __attribute__((ext_vector_type(4))) unsigned short us4;

#define NN 65536

__device__ __forceinline__ unsigned short f2bf(float f) {
  unsigned int u = __float_as_uint(f);
  u += 0x7FFFu + ((u >> 16) & 1u);   // RNE
  return (unsigned short)(u >> 16);
}
__device__ __forceinline__ float bf2f(unsigned short s) {
  return __uint_as_float(((unsigned int)s) << 16);
}
__device__ __forceinline__ f32x4 mfma16(short8 a, short8 b, f32x4 c) {
  return __builtin_amdgcn_mfma_f32_16x16x32_bf16(a, b, c, 0, 0, 0);
}
__device__ __forceinline__ float sigmoidf_(float v) { return 1.0f / (1.0f + __expf(-v)); }
__device__ __forceinline__ float ftanh(float v) { return 1.0f - 2.0f / (__expf(2.0f * v) + 1.0f); }

// ---------------- weight prep ----------------
// frag layout: [kt][t][lane][8]; lane holds B[k = kt*32+8*(lane>>4)+j8][gcol]
// gcol = (t>>1)*32 + 2*(lane&15) + (t&1)   (pair-interleaved columns)
__global__ void prep_all(const float* __restrict__ Wf, const float* __restrict__ Uf,
                         const float* __restrict__ Wiou, const float* __restrict__ Uiou,
                         unsigned short* __restrict__ ws) {
  int idx = blockIdx.x * 256 + threadIdx.x;          // 589824 total
  if (idx < 81920) {                                  // Bwf [10][16][64][8]
    int j = idx & 7, lane = (idx >> 3) & 63, t = (idx >> 9) & 15, kt = idx >> 13;
    int k = kt*32 + ((lane >> 4) << 3) + j;
    int col = (t >> 1)*32 + 2*(lane & 15) + (t & 1);
    ws[idx] = f2bf(k < 300 ? Wf[col*300 + k] : 0.0f);
  } else if (idx < 147456) {                          // Buf [8][16][64][8]
    int i = idx - 81920;
    int j = i & 7, lane = (i >> 3) & 63, t = (i >> 9) & 15, kt = i >> 13;
    int k = kt*32 + ((lane >> 4) << 3) + j;
    int col = (t >> 1)*32 + 2*(lane & 15) + (t & 1);
    ws[idx] = f2bf(Uf[col*256 + k]);
  } else {                                            // Biou [18][48][64][8]; t = cb*3+gate
    int i = idx - 147456;
    int j = i & 7, lane = (i >> 3) & 63;
    int rest = i >> 9, t = rest % 48, kt = rest / 48;
    int k = kt*32 + ((lane >> 4) << 3) + j;
    int cb = t / 3, gate = t % 3;
    int g = gate*256 + (cb >> 1)*32 + 2*(lane & 15) + (cb & 1);
    float v = (k < 320) ? (k < 300 ? Wiou[g*300 + k] : 0.0f) : Uiou[g*256 + (k - 320)];
    ws[idx] = f2bf(v);
  }
}

// ---------------- fused cell ----------------
__global__ __launch_bounds__(512, 4) void fused_cell(
    const float* __restrict__ x, const float* __restrict__ h_msgs,
    const float* __restrict__ c_msgs,
    const float* __restrict__ b_iou, const float* __restrict__ b_Uiou,
    const float* __restrict__ bWf, const float* __restrict__ bUf,
    const unsigned short* __restrict__ Bwf, const unsigned short* __restrict__ Buf,
    const unsigned short* __restrict__ Biou,
    float* __restrict__ out_h, float* __restrict__ out_c) {
  __shared__ alignas(16) char smem[71168];
  unsigned short* Axh = (unsigned short*)smem;            // [32][584]  37376 B
  unsigned short* Hm  = (unsigned short*)(smem + 37376);  // [32][264]  16896 B
  unsigned int*  wfs32 = (unsigned int*)(smem + 54272);   // [32][132]  16896 B (packed wf pair)

  const int tid = threadIdx.x;
  const int n0 = blockIdx.x * 32;
  const int wave = tid >> 6, lane = tid & 63;
  const int lrow = lane & 15, lgrp = lane >> 4;
  const int nl = wave;                 // wave owns node nl of each 8-node chunk
  const int pb = wave*32 + 2*lrow;     // this lane's global column pair base
  const f32x4 fz = {0.0f, 0.0f, 0.0f, 0.0f};

  f32x4 hvN[4];                        // in-flight h_msgs for NEXT chunk

  auto issue_h = [&](int chunk) {
    const float* hp = h_msgs + (size_t)(n0 + chunk*8 + nl)*1024 + lane*4;
#pragma unroll
    for (int k = 0; k < 4; ++k) hvN[k] = *(const f32x4*)(hp + k*256);
  };
  auto write_h = [&](int chunk) {      // regs -> Hm + h_tild -> Axh
    f32x4 s = fz;
#pragma unroll
    for (int k = 0; k < 4; ++k) {
      us4 o;
#pragma unroll
      for (int e = 0; e < 4; ++e) { s[e] += hvN[k][e]; o[e] = f2bf(hvN[k][e]); }
      *(us4*)&Hm[(nl*4 + k)*264 + lane*4] = o;
    }
    us4 ht;
#pragma unroll
    for (int e = 0; e < 4; ++e) ht[e] = f2bf(s[e]);
    *(us4*)&Axh[(chunk*8 + nl)*584 + 320 + lane*4] = ht;
  };

  auto uh_gemm = [&](f32x4 a2[2][2]) {
    const unsigned short* bp = Buf + ((wave*2)*64 + lane)*8;
    short8 b0 = *(const short8*)bp;
    short8 b1 = *(const short8*)(bp + 512);
#pragma unroll
    for (int ks = 0; ks < 8; ++ks) {
      short8 nb0 = b0, nb1 = b1;
      if (ks < 7) {
        const unsigned short* np = Buf + (((ks+1)*16 + wave*2)*64 + lane)*8;
        nb0 = *(const short8*)np;
        nb1 = *(const short8*)(np + 512);
      }
#pragma unroll
      for (int rt = 0; rt < 2; ++rt) {
        short8 a = *(const short8*)&Hm[(rt*16 + lrow)*264 + ks*32 + lgrp*8];
        a2[rt][0] = mfma16(a, b0, a2[rt][0]);
        a2[rt][1] = mfma16(a, b1, a2[rt][1]);
      }
      b0 = nb0; b1 = nb1;
    }
  };

  // ---- prologue: issue h0, stage x, write Hm0, issue h1
  issue_h(0);
  for (int i = tid; i < 32*80; i += 512) {
    int r = i / 80, c4 = i - r*80;
    f32x4 v = fz;
    if (c4 < 75) v = *(const f32x4*)&x[(size_t)(n0 + r)*300 + c4*4];
    us4 o;
#pragma unroll
    for (int e = 0; e < 4; ++e) o[e] = f2bf(v[e]);
    *(us4*)&Axh[r*584 + c4*4] = o;
  }
  write_h(0);
  issue_h(1);
  __syncthreads();                     // B1: Axh-x + Hm0 ready

  // ---- wf GEMM: [32x320]x[320x256] -> wfs32 (packed col-pair, +bias)
  {
    const unsigned short* bp = Bwf + ((wave*2)*64 + lane)*8;
    short8 b0 = *(const short8*)bp;
    short8 b1 = *(const short8*)(bp + 512);
    f32x4 w00 = fz, w01 = fz, w10 = fz, w11 = fz;
#pragma unroll
    for (int ks = 0; ks < 10; ++ks) {
      short8 nb0 = b0, nb1 = b1;
      if (ks < 9) {
        const unsigned short* np = Bwf + (((ks+1)*16 + wave*2)*64 + lane)*8;
        nb0 = *(const short8*)np;
        nb1 = *(const short8*)(np + 512);
      }
      short8 a0 = *(const short8*)&Axh[lrow*584 + ks*32 + lgrp*8];
      short8 a1 = *(const short8*)&Axh[(16 + lrow)*584 + ks*32 + lgrp*8];
      w00 = mfma16(a0, b0, w00); w10 = mfma16(a1, b0, w10);
      w01 = mfma16(a0, b1, w01); w11 = mfma16(a1, b1, w11);
      b0 = nb0; b1 = nb1;
    }
    f32x2 wb = *(const f32x2*)&bWf[pb];
#pragma unroll
    for (int r = 0; r < 4; ++r) {
      wfs32[(lgrp*4 + r)*132 + wave*16 + lrow] =
          (unsigned int)f2bf(w00[r] + wb[0]) | ((unsigned int)f2bf(w01[r] + wb[1]) << 16);
      wfs32[(16 + lgrp*4 + r)*132 + wave*16 + lrow] =
          (unsigned int)f2bf(w10[r] + wb[0]) | ((unsigned int)f2bf(w11[r] + wb[1]) << 16);
    }
  }
  // no barrier: wfs32 columns are wave-private

  const f32x2 buP = *(const f32x2*)&bUf[pb];

  // ---- 4 chunks: uh GEMM + in-register f-gates/c_tild (pair-vectorized)
#pragma unroll
  for (int chunk = 0; chunk < 4; ++chunk) {
    f32x4 a2[2][2] = {{fz, fz}, {fz, fz}};
    uh_gemm(a2);
    __syncthreads();                   // A: all Hm(chunk) reads done
    if (chunk < 3) {
      write_h(chunk + 1);
      if (chunk < 2) issue_h(chunk + 2);
    }
    // cm: 8 x dwordx2 (128-B segments per 16-lane group)
    f32x2 cm[2][4];
#pragma unroll
    for (int rt = 0; rt < 2; ++rt) {
      const float* cp = c_msgs + (size_t)(n0 + chunk*8 + rt*4 + lgrp)*1024 + pb;
#pragma unroll
      for (int r = 0; r < 4; ++r) cm[rt][r] = *(const f32x2*)(cp + r*256);
    }
#pragma unroll
    for (int rt = 0; rt < 2; ++rt) {
      int node = chunk*8 + rt*4 + lgrp;
      unsigned int wp = wfs32[node*132 + wave*16 + lrow];
      float wf0 = bf2f((unsigned short)(wp & 0xFFFFu));
      float wf1 = bf2f((unsigned short)(wp >> 16));
      float s0 = 0.0f, s1 = 0.0f;
#pragma unroll
      for (int r = 0; r < 4; ++r) {
        s0 += sigmoidf_(a2[rt][0][r] + wf0 + buP[0]) * cm[rt][r][0];
        s1 += sigmoidf_(a2[rt][1][r] + wf1 + buP[1]) * cm[rt][r][1];
      }
      f32x2 ct2 = {s0, s1};
      *(f32x2*)&out_c[(size_t)(n0 + node)*256 + pb] = ct2;   // c_tild
    }
    __syncthreads();                   // B: Hm(next) ready / final: ct visible
  }

  // ---- iou GEMM: [32x576]x[576x768]; 2 passes over row-halves rt.
  // Per pass: col-tile pair (2w, 2w+1) x 3 gates -> lane owns col pair pb.
#pragma unroll 1
  for (int rt = 0; rt < 2; ++rt) {
    f32x4 aI0 = fz, aO0 = fz, aU0 = fz, aI1 = fz, aO1 = fz, aU1 = fz;
    const unsigned short* bp0 = Biou + ((size_t)(wave*6)*64 + lane)*8;
    short8 bi0 = *(const short8*)(bp0);
    short8 bo0 = *(const short8*)(bp0 + 512);
    short8 bu0 = *(const short8*)(bp0 + 1024);
    short8 bi1 = *(const short8*)(bp0 + 1536);
    short8 bo1 = *(const short8*)(bp0 + 2048);
    short8 bu1 = *(const short8*)(bp0 + 2560);
#pragma unroll
    for (int ks = 0; ks < 18; ++ks) {
      short8 ni0 = bi0, no0 = bo0, nu0 = bu0, ni1 = bi1, no1 = bo1, nu1 = bu1;
      if (ks < 17) {
        const unsigned short* np = Biou + ((size_t)((ks+1)*48 + wave*6)*64 + lane)*8;
        ni0 = *(const short8*)(np);
        no0 = *(const short8*)(np + 512);
        nu0 = *(const short8*)(np + 1024);
        ni1 = *(const short8*)(np + 1536);
        no1 = *(const short8*)(np + 2048);
        nu1 = *(const short8*)(np + 2560);
      }
      short8 a = *(const short8*)&Axh[(rt*16 + lrow)*584 + ks*32 + lgrp*8];
      aI0 = mfma16(a, bi0, aI0); aO0 = mfma16(a, bo0, aO0); aU0 = mfma16(a, bu0, aU0);
      aI1 = mfma16(a, bi1, aI1); aO1 = mfma16(a, bo1, aO1); aU1 = mfma16(a, bu1, aU1);
      bi0 = ni0; bo0 = no0; bu0 = nu0; bi1 = ni1; bo1 = no1; bu1 = nu1;
    }
    f32x2 bI = {b_iou[pb]       + b_Uiou[pb],       b_iou[pb+1]       + b_Uiou[pb+1]};
    f32x2 bO = {b_iou[256 + pb] + b_Uiou[256 + pb], b_iou[257 + pb]   + b_Uiou[257 + pb]};
    f32x2 bU = {b_iou[512 + pb] + b_Uiou[512 + pb], b_iou[513 + pb]   + b_Uiou[513 + pb]};
    // direct epilogue: rows rt*16+lgrp*4+r, col pair pb (128-B segments)
#pragma unroll
    for (int r = 0; r < 4; ++r) {
      size_t base = (size_t)(n0 + rt*16 + lgrp*4 + r)*256 + pb;
      f32x2 ctl = *(const f32x2*)&out_c[base];      // c_tild (block-visible)
      float i0 = sigmoidf_(aI0[r] + bI[0]);
      float o0 = sigmoidf_(aO0[r] + bO[0]);
      float u0 = ftanh(aU0[r] + bU[0]);
      float i1 = sigmoidf_(aI1[r] + bI[1]);
      float o1 = sigmoidf_(aO1[r] + bO[1]);
      float u1 = ftanh(aU1[r] + bU[1]);
      float c0 = i0*u0 + ctl[0];
      float c1 = i1*u1 + ctl[1];
      f32x2 cv = {c0, c1};
      f32x2 hv = {o0 * ftanh(c0), o1 * ftanh(c1)};
      *(f32x2*)&out_c[base] = cv;
      *(f32x2*)&out_h[base] = hv;
    }
  }
}

extern "C" void kernel_launch(void* const* d_in, const int* in_sizes, int n_in,
                              void* d_out, int out_size, void* d_ws, size_t ws_size,
                              hipStream_t stream) {
  const float* x      = (const float*)d_in[0];
  const float* h_msgs = (const float*)d_in[1];
  const float* c_msgs = (const float*)d_in[2];
  const float* W_iou  = (const float*)d_in[3];
  const float* b_iou  = (const float*)d_in[4];
  const float* U_iou  = (const float*)d_in[5];
  const float* b_Uiou = (const float*)d_in[6];
  const float* W_f    = (const float*)d_in[7];
  const float* b_Wf   = (const float*)d_in[8];
  const float* U_f    = (const float*)d_in[9];
  const float* b_Uf   = (const float*)d_in[10];

  unsigned short* ws   = (unsigned short*)d_ws;
  unsigned short* Bwf  = ws;                    // [10][16][64][8]
  unsigned short* Buf  = ws + 81920;            // [8][16][64][8]
  unsigned short* Biou = ws + 147456;           // [18][48][64][8]

  float* h_slot = (float*)d_out;
  float* c_slot = h_slot + (size_t)NN*256;

  prep_all<<<2304, 256, 0, stream>>>(W_f, U_f, W_iou, U_iou, ws);
  fused_cell<<<NN/32, 512, 0, stream>>>(x, h_msgs, c_msgs, b_iou, b_Uiou,
                                        b_Wf, b_Uf, Bwf, Buf, Biou, h_slot, c_slot);
}

// Round 13
// 279.513 us; speedup vs baseline: 4.5139x; 4.5139x over previous
//
#include <hip/hip_runtime.h>

// ChildSumTreeLSTMCell — round 13: revert to R8 (best verified skeleton) +
// s_setprio around MFMA K-loops (T5). No liveness/structural changes: R9-R12
// all regressed via loop-carried scratch spill at the 128 unified-VGPR cliff.
// 32 nodes/block, 512 threads, 2 blocks/CU; in-register f-gates/c_tild;
// c_tild staged through global c-slot; iou in 2 register-lean passes.

typedef __attribute__((ext_vector_type(8))) short short8;
typedef __attribute__((ext_vector_type(4))) float f32x4;
typedef __attribute__((ext_vector_type(4))) unsigned short us4;
typedef __attribute__((ext_vector_type(4))) unsigned int u32x4;

#define NN 65536

__device__ __forceinline__ unsigned short f2bf(float f) {
  unsigned int u = __float_as_uint(f);
  u += 0x7FFFu + ((u >> 16) & 1u);   // RNE
  return (unsigned short)(u >> 16);
}
__device__ __forceinline__ float bf2f(unsigned short s) {
  return __uint_as_float(((unsigned int)s) << 16);
}
__device__ __forceinline__ f32x4 mfma16(short8 a, short8 b, f32x4 c) {
  return __builtin_amdgcn_mfma_f32_16x16x32_bf16(a, b, c, 0, 0, 0);
}
__device__ __forceinline__ float sigmoidf_(float v) { return 1.0f / (1.0f + __expf(-v)); }
__device__ __forceinline__ float ftanh(float v) { return 1.0f - 2.0f / (__expf(2.0f * v) + 1.0f); }

// ---------------- weight prep ----------------
// frag layout: [kt][ct][lane][8]; lane holds B[k=kt*32+8*(lane>>4)+j][col=ct*16+(lane&15)]
__global__ void prep_all(const float* __restrict__ Wf, const float* __restrict__ Uf,
                         const float* __restrict__ Wiou, const float* __restrict__ Uiou,
                         unsigned short* __restrict__ ws) {
  int idx = blockIdx.x * 256 + threadIdx.x;          // 589824 total
  if (idx < 81920) {                                  // Bwf [10][16][64][8]
    int j = idx & 7, lane = (idx >> 3) & 63, ct = (idx >> 9) & 15, kt = idx >> 13;
    int k = kt*32 + ((lane >> 4) << 3) + j, col = ct*16 + (lane & 15);
    ws[idx] = f2bf(k < 300 ? Wf[col*300 + k] : 0.0f);
  } else if (idx < 147456) {                          // Buf [8][16][64][8]
    int i = idx - 81920;
    int j = i & 7, lane = (i >> 3) & 63, ct = (i >> 9) & 15, kt = i >> 13;
    int k = kt*32 + ((lane >> 4) << 3) + j, col = ct*16 + (lane & 15);
    ws[idx] = f2bf(Uf[col*256 + k]);
  } else {                                            // Biou [18][48][64][8]; ct = cb*3+gate
    int i = idx - 147456;
    int j = i & 7, lane = (i >> 3) & 63;
    int rest = i >> 9, ct = rest % 48, kt = rest / 48;
    int k = kt*32 + ((lane >> 4) << 3) + j;
    int g = (ct % 3)*256 + (ct/3)*16 + (lane & 15);
    float v = (k < 320) ? (k < 300 ? Wiou[g*300 + k] : 0.0f) : Uiou[g*256 + (k - 320)];
    ws[idx] = f2bf(v);
  }
}

// ---------------- fused cell ----------------
__global__ __launch_bounds__(512, 4) void fused_cell(
    const float* __restrict__ x, const float* __restrict__ h_msgs,
    const float* __restrict__ c_msgs,
    const float* __restrict__ b_iou, const float* __restrict__ b_Uiou,
    const float* __restrict__ bWf, const float* __restrict__ bUf,
    const unsigned short* __restrict__ Bwf, const unsigned short* __restrict__ Buf,
    const unsigned short* __restrict__ Biou,
    float* __restrict__ out_h, float* __restrict__ out_c) {
  __shared__ alignas(16) char smem[71168];
  unsigned short* Axh = (unsigned short*)smem;            // [32][584]  37376 B
  unsigned short* Hm  = (unsigned short*)(smem + 37376);  // [32][264]  16896 B
  unsigned short* wfs = (unsigned short*)(smem + 54272);  // [32][264]  16896 B
  unsigned int*   IUO = (unsigned int*)(smem + 37376);    // [32][260]  33280 B overlay

  const int tid = threadIdx.x;
  const int n0 = blockIdx.x * 32;
  const int wave = tid >> 6, lane = tid & 63;
  const int lrow = lane & 15, lgrp = lane >> 4;
  const int nl = wave;                 // wave owns node nl of each 8-node chunk
  const f32x4 fz = {0.0f, 0.0f, 0.0f, 0.0f};

  f32x4 hvN[4];                        // in-flight h_msgs for NEXT chunk

  auto issue_h = [&](int chunk) {      // global -> regs (issue only)
    int node = n0 + chunk*8 + nl;
    const float* hp = h_msgs + (size_t)node*1024 + lane*4;
#pragma unroll
    for (int k = 0; k < 4; ++k) hvN[k] = *(const f32x4*)(hp + k*256);
  };

  auto write_h = [&](int chunk) {      // regs -> Hm + h_tild -> Axh
    f32x4 s = fz;
#pragma unroll
    for (int k = 0; k < 4; ++k) {
      us4 o;
#pragma unroll
      for (int e = 0; e < 4; ++e) { s[e] += hvN[k][e]; o[e] = f2bf(hvN[k][e]); }
      *(us4*)&Hm[(nl*4 + k)*264 + lane*4] = o;
    }
    us4 ht;
#pragma unroll
    for (int e = 0; e < 4; ++e) ht[e] = f2bf(s[e]);
    *(us4*)&Axh[(chunk*8 + nl)*584 + 320 + lane*4] = ht;
  };

  auto uh_gemm = [&](f32x4 a2[2][2]) {
    const unsigned short* bp = Buf + ((wave*2)*64 + lane)*8;
    short8 b0 = *(const short8*)bp;
    short8 b1 = *(const short8*)(bp + 512);
    __builtin_amdgcn_s_setprio(1);
#pragma unroll
    for (int ks = 0; ks < 8; ++ks) {
      short8 nb0 = b0, nb1 = b1;
      if (ks < 7) {
        const unsigned short* np = Buf + (((ks+1)*16 + wave*2)*64 + lane)*8;
        nb0 = *(const short8*)np;
        nb1 = *(const short8*)(np + 512);
      }
#pragma unroll
      for (int rt = 0; rt < 2; ++rt) {
        short8 a = *(const short8*)&Hm[(rt*16 + lrow)*264 + ks*32 + lgrp*8];
        a2[rt][0] = mfma16(a, b0, a2[rt][0]);
        a2[rt][1] = mfma16(a, b1, a2[rt][1]);
      }
      b0 = nb0; b1 = nb1;
    }
    __builtin_amdgcn_s_setprio(0);
  };

  // ---- prologue: issue h0, stage x, write Hm0, issue h1
  issue_h(0);
  for (int i = tid; i < 32*80; i += 512) {
    int r = i / 80, c4 = i - r*80;
    f32x4 v = fz;
    if (c4 < 75) v = *(const f32x4*)&x[(size_t)(n0 + r)*300 + c4*4];
    us4 o;
#pragma unroll
    for (int e = 0; e < 4; ++e) o[e] = f2bf(v[e]);
    *(us4*)&Axh[r*584 + c4*4] = o;
  }
  write_h(0);
  issue_h(1);
  __syncthreads();                     // Axh(x) + Hm0 ready

  // ---- wf GEMM: [32 x 320] x [320 x 256] -> wfs (bf16, +bias), wave-private cols
  {
    const unsigned short* bp = Bwf + ((wave*2)*64 + lane)*8;
    short8 b0 = *(const short8*)bp;
    short8 b1 = *(const short8*)(bp + 512);
    f32x4 w00 = fz, w01 = fz, w10 = fz, w11 = fz;
    __builtin_amdgcn_s_setprio(1);
#pragma unroll
    for (int ks = 0; ks < 10; ++ks) {
      short8 nb0 = b0, nb1 = b1;
      if (ks < 9) {
        const unsigned short* np = Bwf + (((ks+1)*16 + wave*2)*64 + lane)*8;
        nb0 = *(const short8*)np;
        nb1 = *(const short8*)(np + 512);
      }
      short8 a0 = *(const short8*)&Axh[lrow*584 + ks*32 + lgrp*8];
      short8 a1 = *(const short8*)&Axh[(16 + lrow)*584 + ks*32 + lgrp*8];
      w00 = mfma16(a0, b0, w00); w10 = mfma16(a1, b0, w10);
      w01 = mfma16(a0, b1, w01); w11 = mfma16(a1, b1, w11);
      b0 = nb0; b1 = nb1;
    }
    __builtin_amdgcn_s_setprio(0);
#pragma unroll
    for (int ct = 0; ct < 2; ++ct) {
      int col = wave*32 + ct*16 + lrow;
      float bias = bWf[col];
      f32x4 v0 = ct ? w01 : w00, v1 = ct ? w11 : w10;
#pragma unroll
      for (int r = 0; r < 4; ++r) {
        wfs[(lgrp*4 + r)*264 + col]      = f2bf(v0[r] + bias);
        wfs[(16 + lgrp*4 + r)*264 + col] = f2bf(v1[r] + bias);
      }
    }
  }
  __syncthreads();                     // wfs visible before chunk0 f-epilogue

  float bu[2];
  bu[0] = bUf[wave*32 + lrow];
  bu[1] = bUf[wave*32 + 16 + lrow];

  // ---- 4 chunks: uh GEMM + fully in-register f-gates/c_tild
#pragma unroll
  for (int chunk = 0; chunk < 4; ++chunk) {
    // issue c_msgs for this lane's (node, col) set: 16 coalesced scalars
    float cm[2][2][4];
#pragma unroll
    for (int rt = 0; rt < 2; ++rt) {
      const float* cp = c_msgs + (size_t)(n0 + chunk*8 + rt*4 + lgrp)*1024 + wave*32 + lrow;
#pragma unroll
      for (int ct2 = 0; ct2 < 2; ++ct2)
#pragma unroll
        for (int r = 0; r < 4; ++r) cm[rt][ct2][r] = cp[r*256 + ct2*16];
    }

    f32x4 a2[2][2] = {{fz, fz}, {fz, fz}};
    uh_gemm(a2);

    // lane holds uh for node rt*4+lgrp, all 4 children, col wave*32+ct2*16+lrow
#pragma unroll
    for (int rt = 0; rt < 2; ++rt) {
      int node = chunk*8 + rt*4 + lgrp;
#pragma unroll
      for (int ct2 = 0; ct2 < 2; ++ct2) {
        int col = wave*32 + ct2*16 + lrow;
        float wfv = bf2f(wfs[node*264 + col]);
        float s = 0.0f;
#pragma unroll
        for (int r = 0; r < 4; ++r) {
          float fg = sigmoidf_(a2[rt][ct2][r] + wfv + bu[ct2]);
          s += fg * cm[rt][ct2][r];
        }
        out_c[(size_t)(n0 + node)*256 + col] = s;   // c_tild, read back at the end
      }
    }
    __syncthreads();                   // all uh reads of Hm(chunk) done
    if (chunk < 3) {
      write_h(chunk + 1);
      if (chunk < 2) issue_h(chunk + 2);
      __syncthreads();                 // Hm(next) ready
    }
  }
  // post-chunk barrier above also separates last wfs reads from IUO overlay

  // ---- iou GEMM: [32 x 576] x [576 x 768]; 2 passes of 1 col-block x 3 gates
#pragma unroll 1
  for (int p = 0; p < 2; ++p) {
    int cb = wave*2 + p;               // col-block in [0,16)
    int ct0 = cb*3;
    int col = cb*16 + lrow;
    f32x4 aI0 = fz, aO0 = fz, aU0 = fz, aI1 = fz, aO1 = fz, aU1 = fz;
    const unsigned short* bp = Biou + ((size_t)ct0*64 + lane)*8;
    short8 bi = *(const short8*)bp;
    short8 bo = *(const short8*)(bp + 512);
    short8 bu8 = *(const short8*)(bp + 1024);
    __builtin_amdgcn_s_setprio(1);
#pragma unroll
    for (int ks = 0; ks < 18; ++ks) {
      short8 ni = bi, no = bo, nu = bu8;
      if (ks < 17) {
        const unsigned short* np = Biou + ((size_t)((ks+1)*48 + ct0)*64 + lane)*8;
        ni = *(const short8*)np;
        no = *(const short8*)(np + 512);
        nu = *(const short8*)(np + 1024);
      }
      short8 a0 = *(const short8*)&Axh[lrow*584 + ks*32 + lgrp*8];
      short8 a1 = *(const short8*)&Axh[(16 + lrow)*584 + ks*32 + lgrp*8];
      aI0 = mfma16(a0, bi, aI0);  aI1 = mfma16(a1, bi, aI1);
      aO0 = mfma16(a0, bo, aO0);  aO1 = mfma16(a1, bo, aO1);
      aU0 = mfma16(a0, bu8, aU0); aU1 = mfma16(a1, bu8, aU1);
      bi = ni; bo = no; bu8 = nu;
    }
    __builtin_amdgcn_s_setprio(0);
    float bI = b_iou[col]       + b_Uiou[col];
    float bO = b_iou[256 + col] + b_Uiou[256 + col];
    float bU = b_iou[512 + col] + b_Uiou[512 + col];
#pragma unroll
    for (int rt = 0; rt < 2; ++rt) {
      f32x4 ai = rt ? aI1 : aI0, ao = rt ? aO1 : aO0, au = rt ? aU1 : aU0;
#pragma unroll
      for (int r = 0; r < 4; ++r) {
        float iv = sigmoidf_(ai[r] + bI);
        float ov = sigmoidf_(ao[r] + bO);
        float uv = ftanh(au[r] + bU);
        IUO[(rt*16 + lgrp*4 + r)*260 + col] =
            (unsigned int)f2bf(iv * uv) | ((unsigned int)f2bf(ov) << 16);
      }
    }
  }
  __syncthreads();

  // ---- final coalesced write: c = iu + c_tild (read back); h = o*tanh(c)
#pragma unroll
  for (int chunk = 0; chunk < 4; ++chunk) {
    int nb = chunk*8 + nl;
    size_t base = (size_t)(n0 + nb)*256 + lane*4;
    u32x4 pk = *(const u32x4*)&IUO[nb*260 + lane*4];
    f32x4 ctl = *(const f32x4*)&out_c[base];   // store-only lines -> L2-visible
    f32x4 hv, cvo;
#pragma unroll
    for (int e = 0; e < 4; ++e) {
      float iu = bf2f((unsigned short)(pk[e] & 0xFFFFu));
      float ov = bf2f((unsigned short)(pk[e] >> 16));
      float c  = iu + ctl[e];
      cvo[e] = c;
      hv[e] = ov * ftanh(c);
    }
    *(f32x4*)&out_h[base] = hv;
    *(f32x4*)&out_c[base] = cvo;
  }
}

extern "C" void kernel_launch(void* const* d_in, const int* in_sizes, int n_in,
                              void* d_out, int out_size, void* d_ws, size_t ws_size,
                              hipStream_t stream) {
  const float* x      = (const float*)d_in[0];
  const float* h_msgs = (const float*)d_in[1];
  const float* c_msgs = (const float*)d_in[2];
  const float* W_iou  = (const float*)d_in[3];
  const float* b_iou  = (const float*)d_in[4];
  const float* U_iou  = (const float*)d_in[5];
  const float* b_Uiou = (const float*)d_in[6];
  const float* W_f    = (const float*)d_in[7];
  const float* b_Wf   = (const float*)d_in[8];
  const float* U_f    = (const float*)d_in[9];
  const float* b_Uf   = (const float*)d_in[10];

  unsigned short* ws   = (unsigned short*)d_ws;
  unsigned short* Bwf  = ws;                    // [10][16][64][8]
  unsigned short* Buf  = ws + 81920;            // [8][16][64][8]
  unsigned short* Biou = ws + 147456;           // [18][48][64][8]

  float* h_slot = (float*)d_out;
  float* c_slot = h_slot + (size_t)NN*256;

  prep_all<<<2304, 256, 0, stream>>>(W_f, U_f, W_iou, U_iou, ws);
  fused_cell<<<NN/32, 512, 0, stream>>>(x, h_msgs, c_msgs, b_iou, b_Uiou,
                                        b_Wf, b_Uf, Bwf, Buf, Biou, h_slot, c_slot);
}